// Round 15
// baseline (681.936 us; speedup 1.0000x reference)
//
#include <hip/hip_runtime.h>
#include <hip/hip_fp16.h>

#define B_  256
#define T_  512
#define I_  64
#define H_  128
#define G_  384
#define HC  256

#define O_OUT0 0ull
#define O_XW1  67108864ull
#define O_WP   167772160ull
#define O_H1F  (O_WP + 196608ull)
#define O_WF16 (O_H1F + 131072ull)

typedef _Float16 h8 __attribute__((ext_vector_type(8)));
typedef _Float16 h2 __attribute__((ext_vector_type(2)));
typedef float    f4 __attribute__((ext_vector_type(4)));

#define MFMA16 __builtin_amdgcn_mfma_f32_16x16x32_f16

__device__ __forceinline__ float sigm(float x)   { return __builtin_amdgcn_rcpf(1.f + __expf(-x)); }
__device__ __forceinline__ float tanh_f(float x) { return 1.f - 2.f * __builtin_amdgcn_rcpf(1.f + __expf(2.f * x)); }

__device__ __forceinline__ void bar_lds() {
    asm volatile("s_waitcnt lgkmcnt(0)\n\ts_barrier" ::: "memory");
}

__device__ __forceinline__ h8 load_w8(const float* src) {
    f4 a = *(const f4*)src;
    f4 b = *(const f4*)(src + 4);
    h8 v;
    v[0]=(_Float16)a[0]; v[1]=(_Float16)a[1]; v[2]=(_Float16)a[2]; v[3]=(_Float16)a[3];
    v[4]=(_Float16)b[0]; v[5]=(_Float16)b[1]; v[6]=(_Float16)b[2]; v[7]=(_Float16)b[3];
    return v;
}

// Prep (x16 path removed — scan_l0 reads f32 x directly): Wih1f->fp16 (48 blocks),
// Wih1b pack-T (192 blocks).
__global__ void prep(const float* __restrict__ Wf, _Float16* __restrict__ wf16,
                     const float* __restrict__ W1b, __half2* __restrict__ wp) {
    const int bid = blockIdx.x;
    const int tid = threadIdx.x;
    if (bid < 48) {            // Wih1f: 12,288 groups of 8
        int i = bid * 256 + tid;
        const float* s = Wf + (size_t)i * 8;
        f4 a = *(const f4*)s, b = *(const f4*)(s + 4);
        h8 v;
        v[0]=(_Float16)a[0]; v[1]=(_Float16)a[1]; v[2]=(_Float16)a[2]; v[3]=(_Float16)a[3];
        v[4]=(_Float16)b[0]; v[5]=(_Float16)b[1]; v[6]=(_Float16)b[2]; v[7]=(_Float16)b[3];
        *(h8*)(wf16 + (size_t)i * 8) = v;
    } else {                   // Wih1b pack-T: 49,152 items
        int i = (bid - 48) * 256 + tid;
        int c = i % G_;
        int k2 = i / G_;
        wp[i] = __halves2half2(__float2half(W1b[c * 256 + 2 * k2]),
                               __float2half(W1b[c * 256 + 2 * k2 + 1]));
    }
}

// ---------------- Layer-0 scan: 4 rows/block + 4-timestep-packed x-MFMAs ----------------
// Batches at A-rows {0,4,8,12}; valid h C-data = reg 0 of every lane.
// x-part packing: A-row r -> batch (r>>2), time-offset (r&3). One 6-MFMA set
// yields gates for FOUR steps: C reg j = step t+j (row lq*4+j = batch lq, toff j).
// x is read as f32 directly (load_w8 converts in-register) — no x16 staging.
// A-frag h reads broadcast via row ln15&12 (conflict-free). Flat MFMA chains.
#define L0_STEP(SB, DB, J, ...) do {                                          \
    h8 ah0 = *(const h8*)&s_h[SB][offh[0]];                                   \
    h8 ah1 = *(const h8*)&s_h[SB][offh[1]];                                   \
    h8 ah2 = *(const h8*)&s_h[SB][offh[2]];                                   \
    h8 ah3 = *(const h8*)&s_h[SB][offh[3]];                                   \
    f4 hRa = z4, hRb = z4, hZa = z4, hZb = z4, hNa = sHn4, hNb = z4;          \
    hRa = MFMA16(ah0, bh[0][0], hRa, 0, 0, 0);                                \
    hZa = MFMA16(ah0, bh[1][0], hZa, 0, 0, 0);                                \
    hNa = MFMA16(ah0, bh[2][0], hNa, 0, 0, 0);                                \
    hRb = MFMA16(ah2, bh[0][2], hRb, 0, 0, 0);                                \
    hZb = MFMA16(ah2, bh[1][2], hZb, 0, 0, 0);                                \
    hNb = MFMA16(ah2, bh[2][2], hNb, 0, 0, 0);                                \
    hRa = MFMA16(ah1, bh[0][1], hRa, 0, 0, 0);                                \
    hZa = MFMA16(ah1, bh[1][1], hZa, 0, 0, 0);                                \
    hNa = MFMA16(ah1, bh[2][1], hNa, 0, 0, 0);                                \
    hRb = MFMA16(ah3, bh[0][3], hRb, 0, 0, 0);                                \
    hZb = MFMA16(ah3, bh[1][3], hZb, 0, 0, 0);                                \
    hNb = MFMA16(ah3, bh[2][3], hNb, 0, 0, 0);                                \
    float r_ = sigm(gR[J] + hRa[0] + hRb[0]);                                 \
    float z_ = sigm(gZ[J] + hZa[0] + hZb[0]);                                 \
    float n_ = tanh_f(gN[J] + r_ * (hNa[0] + hNb[0]));                        \
    float h_ = n_ + z_ * (hF - n_);                                           \
    hF = h_;                                                                  \
    s_h[DB][offw0] = (_Float16)h_;                                            \
    *op = (_Float16)h_; op += ostep;                                          \
    __VA_ARGS__                                                               \
    bar_lds();                                                                \
} while (0)

__launch_bounds__(512, 1)
__global__ void scan_l0(const float* __restrict__ xf,
                        const float* __restrict__ Wih_f, const float* __restrict__ Whh_f,
                        const float* __restrict__ bih_f, const float* __restrict__ bhh_f,
                        const float* __restrict__ Wih_b, const float* __restrict__ Whh_b,
                        const float* __restrict__ bih_b, const float* __restrict__ bhh_b,
                        _Float16* __restrict__ out0) {
    __shared__ __align__(16) _Float16 s_h[2][16 * 128];

    const int tid  = threadIdx.x;
    const int lane = tid & 63;
    const int w    = tid >> 6;           // 0..7
    const int dir  = blockIdx.y;
    const int b0   = blockIdx.x * 4;

    const float* Wih = dir ? Wih_b : Wih_f;
    const float* Whh = dir ? Whh_b : Whh_f;
    const float* bih = dir ? bih_b : bih_f;
    const float* bhh = dir ? bhh_b : bhh_f;

    for (int i = tid; i < 2 * 16 * 128; i += 512) ((_Float16*)s_h)[i] = (_Float16)0.f;

    const int ln15 = lane & 15;
    const int lq   = lane >> 4;
    const int col  = 16 * w + ln15;

    h8 bh[3][4], bx[3][2];
    float seedR = bih[col] + bhh[col];
    float seedZ = bih[H_ + col] + bhh[H_ + col];
    float bihN  = bih[2 * H_ + col];
    float bhhN  = bhh[2 * H_ + col];
#pragma unroll
    for (int g = 0; g < 3; g++) {
        int n = g * H_ + col;
#pragma unroll
        for (int kt = 0; kt < 4; kt++) bh[g][kt] = load_w8(Whh + (size_t)n * H_ + kt * 32 + lq * 8);
#pragma unroll
        for (int kt = 0; kt < 2; kt++) bx[g][kt] = load_w8(Wih + (size_t)n * I_ + kt * 32 + lq * 8);
    }
    const int arow = ln15 & 12;          // broadcast A-read row (conflict-free)
    int offh[4];
#pragma unroll
    for (int kt = 0; kt < 4; kt++)
        offh[kt] = arow * 128 + (((kt * 4 + lq) ^ arow) & 15) * 8;
    const int row0  = lq * 4;
    const int offw0 = row0 * 128 + ((((col >> 3) ^ row0) & 15)) * 8 + (col & 7);

    const f4 z4 = (f4){0.f, 0.f, 0.f, 0.f};
    const f4 sR4 = (f4){seedR, seedR, seedR, seedR};
    const f4 sZ4 = (f4){seedZ, seedZ, seedZ, seedZ};
    const f4 sXn4 = (f4){bihN, bihN, bihN, bihN};
    const f4 sHn4 = (f4){bhhN, bhhN, bhhN, bhhN};

    // packed x lane pointer (f32): batch = b0+(ln15>>2), time-offset = ln15&3.
    const int toff = ln15 & 3;
    const float* xp = xf + ((size_t)(b0 + (ln15 >> 2)) * T_ + (dir ? (T_ - 1 - toff) : toff)) * I_ + lq * 8;
    const int xstep = dir ? -(4 * I_) : (4 * I_);   // 4 timesteps per iter

    _Float16* op = out0 + ((size_t)(b0 + lq) * T_ + (dir ? (T_ - 1) : 0)) * HC + dir * H_ + col;
    const int ostep = dir ? -HC : HC;

    float hF = 0.f;
    f4 gR, gZ, gN;        // current gates, component j = step t+j
    f4 ngR, ngZ, ngN;     // next iter's gates
    h8 xvA0, xvA1;        // x for steps t+4..t+7
    {   // prologue: gates(0..3) from x(0..3); xvA <- x(4..7)
        h8 xc0 = load_w8(xp);
        h8 xc1 = load_w8(xp + 32);
        xp += xstep;
        xvA0 = load_w8(xp);
        xvA1 = load_w8(xp + 32);
        xp += xstep;      // now points at t+8 block
        gR = sR4; gZ = sZ4; gN = sXn4;
        gR = MFMA16(xc0, bx[0][0], gR, 0, 0, 0);
        gZ = MFMA16(xc0, bx[1][0], gZ, 0, 0, 0);
        gN = MFMA16(xc0, bx[2][0], gN, 0, 0, 0);
        gR = MFMA16(xc1, bx[0][1], gR, 0, 0, 0);
        gZ = MFMA16(xc1, bx[1][1], gZ, 0, 0, 0);
        gN = MFMA16(xc1, bx[2][1], gN, 0, 0, 0);
    }
    __syncthreads();

#pragma unroll 1
    for (int t = 0; t < T_; t += 4) {
        L0_STEP(0, 1, 0,
            if (t + 4 < T_) {   // next gate quad from xvA (off critical path)
                ngR = sR4; ngZ = sZ4; ngN = sXn4;
                ngR = MFMA16(xvA0, bx[0][0], ngR, 0, 0, 0);
                ngZ = MFMA16(xvA0, bx[1][0], ngZ, 0, 0, 0);
                ngN = MFMA16(xvA0, bx[2][0], ngN, 0, 0, 0);
                ngR = MFMA16(xvA1, bx[0][1], ngR, 0, 0, 0);
                ngZ = MFMA16(xvA1, bx[1][1], ngZ, 0, 0, 0);
                ngN = MFMA16(xvA1, bx[2][1], ngN, 0, 0, 0);
            }
        );
        L0_STEP(1, 0, 1, );
        L0_STEP(0, 1, 2,
            if (t + 8 < T_) {   // reload xvA <- x(t+8..t+11)
                xvA0 = load_w8(xp);
                xvA1 = load_w8(xp + 32);
                xp += xstep;
            }
        );
        L0_STEP(1, 0, 3,
            gR = ngR; gZ = ngZ; gN = ngN;
        );
    }
}

// ---------------- MFMA GEMM v4: per-block M=64, full N=384 (unchanged) ----------------
__launch_bounds__(256, 1)
__global__ void gemm_xw1(const _Float16* __restrict__ A,
                         const _Float16* __restrict__ Bw,
                         const float* __restrict__ bias,
                         _Float16* __restrict__ C) {
    __shared__ __align__(16) _Float16 sA[2][64 * 64];
    __shared__ __align__(16) _Float16 sB[2][384 * 64];
    const int tid  = threadIdx.x;
    const int lane = tid & 63;
    const int w    = tid >> 6;
    const int wm   = w & 1, wn = w >> 1;
    const int ln15 = lane & 15, lq = lane >> 4;
    const size_t m0 = (size_t)blockIdx.x * 64;

    f4 acc[2][12] = {};

    int aRow[2], aG[2], aOff[2];
#pragma unroll
    for (int k = 0; k < 2; k++) {
        int idx = k * 256 + tid;
        aRow[k] = idx >> 3; aG[k] = idx & 7;
        aOff[k] = aRow[k] * 64 + ((aG[k] ^ (aRow[k] & 7)) & 7) * 8;
    }
    int bRow[12], bG[12], bOff[12];
#pragma unroll
    for (int k = 0; k < 12; k++) {
        int idx = k * 256 + tid;
        bRow[k] = idx >> 3; bG[k] = idx & 7;
        bOff[k] = bRow[k] * 64 + ((bG[k] ^ (bRow[k] & 7)) & 7) * 8;
    }
    int offA[2][2], offB[12][2];
#pragma unroll
    for (int mt = 0; mt < 2; mt++)
#pragma unroll
        for (int kt = 0; kt < 2; kt++) {
            int row = wm * 32 + mt * 16 + ln15;
            offA[mt][kt] = row * 64 + (((kt * 4 + lq) ^ (row & 7)) & 7) * 8;
        }
#pragma unroll
    for (int nt = 0; nt < 12; nt++)
#pragma unroll
        for (int kt = 0; kt < 2; kt++) {
            int row = wn * 192 + nt * 16 + ln15;
            offB[nt][kt] = row * 64 + (((kt * 4 + lq) ^ (row & 7)) & 7) * 8;
        }

    {   // prologue: chunk 0 -> buf 0
        h8 av[2], bv[12];
#pragma unroll
        for (int k = 0; k < 2; k++) av[k] = *(const h8*)(A + (m0 + aRow[k]) * 256 + aG[k] * 8);
#pragma unroll
        for (int k = 0; k < 12; k++) bv[k] = *(const h8*)(Bw + (size_t)bRow[k] * 256 + bG[k] * 8);
#pragma unroll
        for (int k = 0; k < 2; k++) *(h8*)&sA[0][aOff[k]] = av[k];
#pragma unroll
        for (int k = 0; k < 12; k++) *(h8*)&sB[0][bOff[k]] = bv[k];
        bar_lds();
    }

#pragma unroll
    for (int c = 0; c < 4; c++) {
        const int cur = c & 1;
        h8 av[2], bv[12];
        if (c < 3) {
#pragma unroll
            for (int k = 0; k < 2; k++)
                av[k] = *(const h8*)(A + (m0 + aRow[k]) * 256 + (c + 1) * 64 + aG[k] * 8);
#pragma unroll
            for (int k = 0; k < 12; k++)
                bv[k] = *(const h8*)(Bw + (size_t)bRow[k] * 256 + (c + 1) * 64 + bG[k] * 8);
        }
#pragma unroll
        for (int kt = 0; kt < 2; kt++) {
            h8 af0 = *(const h8*)&sA[cur][offA[0][kt]];
            h8 af1 = *(const h8*)&sA[cur][offA[1][kt]];
#pragma unroll
            for (int nt = 0; nt < 12; nt++) {
                h8 bf = *(const h8*)&sB[cur][offB[nt][kt]];
                acc[0][nt] = MFMA16(af0, bf, acc[0][nt], 0, 0, 0);
                acc[1][nt] = MFMA16(af1, bf, acc[1][nt], 0, 0, 0);
            }
        }
        if (c < 3) {
#pragma unroll
            for (int k = 0; k < 2; k++) *(h8*)&sA[cur ^ 1][aOff[k]] = av[k];
#pragma unroll
            for (int k = 0; k < 12; k++) *(h8*)&sB[cur ^ 1][bOff[k]] = bv[k];
            bar_lds();
        }
    }
#pragma unroll
    for (int nt = 0; nt < 12; nt++) {
        int col = wn * 192 + nt * 16 + ln15;
        float bb = bias[col];
        int pcol = (col < 256) ? ((col & 127) * 2 + (col >> 7)) : col;
#pragma unroll
        for (int mt = 0; mt < 2; mt++) {
            size_t row = m0 + wm * 32 + mt * 16 + lq * 4;
#pragma unroll
            for (int reg = 0; reg < 4; reg++)
                C[(row + reg) * G_ + pcol] = (_Float16)(acc[mt][nt][reg] + bb);
        }
    }
}

// ---------------- Layer-1 fwd scan: 8 waves, 4 rows/block (known-good) ----------------
__launch_bounds__(512, 1)
__global__ void scan_l1(const _Float16* __restrict__ xw1,
                        const float* __restrict__ Whh,
                        const float* __restrict__ bhh,
                        float* __restrict__ h1f) {
    __shared__ __align__(16) _Float16 s_h[2][16 * 128];

    const int tid  = threadIdx.x;
    const int lane = tid & 63;
    const int w    = tid >> 6;
    const int b0   = blockIdx.x * 4;

    for (int i = tid; i < 2 * 16 * 128; i += 512) ((_Float16*)s_h)[i] = (_Float16)0.f;

    const int ln15 = lane & 15;
    const int lq   = lane >> 4;
    const int col  = 16 * w + ln15;

    h8 bh[3][4];
    float bhhF[3];
#pragma unroll
    for (int g = 0; g < 3; g++) {
        int n = g * H_ + col;
        bhhF[g] = bhh[n];
#pragma unroll
        for (int kt = 0; kt < 4; kt++) bh[g][kt] = load_w8(Whh + (size_t)n * H_ + kt * 32 + lq * 8);
    }
    const int arow = ln15 & 12;
    int offh[4];
#pragma unroll
    for (int kt = 0; kt < 4; kt++)
        offh[kt] = arow * 128 + (((kt * 4 + lq) ^ arow) & 15) * 8;
    const int row0  = lq * 4;
    const int offw0 = row0 * 128 + ((((col >> 3) ^ row0) & 15)) * 8 + (col & 7);

    const _Float16* rzbase = xw1 + ((size_t)(b0 + lq) * T_) * G_ + 2 * col;
    const _Float16* nbase  = xw1 + ((size_t)(b0 + lq) * T_) * G_ + 256 + col;

    const f4 z4 = (f4){0.f, 0.f, 0.f, 0.f};
    const f4 sR4 = (f4){bhhF[0], bhhF[0], bhhF[0], bhhF[0]};
    const f4 sZ4 = (f4){bhhF[1], bhhF[1], bhhF[1], bhhF[1]};
    const f4 sN4 = (f4){bhhF[2], bhhF[2], bhhF[2], bhhF[2]};

    __syncthreads();

    float hF = 0.f;
    h2 rzA = *(const h2*)(rzbase);
    h2 rzB = *(const h2*)(rzbase + G_);
    _Float16 nA = *nbase;
    _Float16 nB = *(nbase + G_);
    const _Float16* rzP2 = rzbase + 2 * G_;
    const _Float16* nP2  = nbase  + 2 * G_;
    const _Float16* rzP3 = rzbase + 3 * G_;
    const _Float16* nP3  = nbase  + 3 * G_;

#pragma unroll 1
    for (int s = 0; s < T_; s += 2) {
        {   // even step: read s_h[0] -> write s_h[1]
            h8 ah0 = *(const h8*)&s_h[0][offh[0]];
            h8 ah1 = *(const h8*)&s_h[0][offh[1]];
            h8 ah2 = *(const h8*)&s_h[0][offh[2]];
            h8 ah3 = *(const h8*)&s_h[0][offh[3]];
            float xr = (float)rzA[0], xz = (float)rzA[1], xn = (float)nA;
            if (s + 2 < T_) {
                rzA = *(const h2*)rzP2;
                nA  = *nP2;
                rzP2 += 2 * G_; nP2 += 2 * G_;
            }
            f4 hRa = sR4, hRb = z4, hZa = sZ4, hZb = z4, hNa = sN4, hNb = z4;
            hRa = MFMA16(ah0, bh[0][0], hRa, 0, 0, 0);
            hZa = MFMA16(ah0, bh[1][0], hZa, 0, 0, 0);
            hNa = MFMA16(ah0, bh[2][0], hNa, 0, 0, 0);
            hRb = MFMA16(ah2, bh[0][2], hRb, 0, 0, 0);
            hZb = MFMA16(ah2, bh[1][2], hZb, 0, 0, 0);
            hNb = MFMA16(ah2, bh[2][2], hNb, 0, 0, 0);
            hRa = MFMA16(ah1, bh[0][1], hRa, 0, 0, 0);
            hZa = MFMA16(ah1, bh[1][1], hZa, 0, 0, 0);
            hNa = MFMA16(ah1, bh[2][1], hNa, 0, 0, 0);
            hRb = MFMA16(ah3, bh[0][3], hRb, 0, 0, 0);
            hZb = MFMA16(ah3, bh[1][3], hZb, 0, 0, 0);
            hNb = MFMA16(ah3, bh[2][3], hNb, 0, 0, 0);
            float r = sigm(xr + hRa[0] + hRb[0]);
            float z = sigm(xz + hZa[0] + hZb[0]);
            float n = tanh_f(xn + r * (hNa[0] + hNb[0]));
            float h = n + z * (hF - n);
            hF = h;
            s_h[1][offw0] = (_Float16)h;
            bar_lds();
        }
        {   // odd step: read s_h[1] -> write s_h[0]
            h8 ah0 = *(const h8*)&s_h[1][offh[0]];
            h8 ah1 = *(const h8*)&s_h[1][offh[1]];
            h8 ah2 = *(const h8*)&s_h[1][offh[2]];
            h8 ah3 = *(const h8*)&s_h[1][offh[3]];
            float xr = (float)rzB[0], xz = (float)rzB[1], xn = (float)nB;
            if (s + 3 < T_) {
                rzB = *(const h2*)rzP3;
                nB  = *nP3;
                rzP3 += 2 * G_; nP3 += 2 * G_;
            }
            f4 hRa = sR4, hRb = z4, hZa = sZ4, hZb = z4, hNa = sN4, hNb = z4;
            hRa = MFMA16(ah0, bh[0][0], hRa, 0, 0, 0);
            hZa = MFMA16(ah0, bh[1][0], hZa, 0, 0, 0);
            hNa = MFMA16(ah0, bh[2][0], hNa, 0, 0, 0);
            hRb = MFMA16(ah2, bh[0][2], hRb, 0, 0, 0);
            hZb = MFMA16(ah2, bh[1][2], hZb, 0, 0, 0);
            hNb = MFMA16(ah2, bh[2][2], hNb, 0, 0, 0);
            hRa = MFMA16(ah1, bh[0][1], hRa, 0, 0, 0);
            hZa = MFMA16(ah1, bh[1][1], hZa, 0, 0, 0);
            hNa = MFMA16(ah1, bh[2][1], hNa, 0, 0, 0);
            hRb = MFMA16(ah3, bh[0][3], hRb, 0, 0, 0);
            hZb = MFMA16(ah3, bh[1][3], hZb, 0, 0, 0);
            hNb = MFMA16(ah3, bh[2][3], hNb, 0, 0, 0);
            float r = sigm(xr + hRa[0] + hRb[0]);
            float z = sigm(xz + hZa[0] + hZb[0]);
            float n = tanh_f(xn + r * (hNa[0] + hNb[0]));
            float h = n + z * (hF - n);
            hF = h;
            s_h[0][offw0] = (_Float16)h;
            bar_lds();
        }
    }
    h1f[(size_t)(b0 + lq) * H_ + col] = hF;
}

// ---------------- Tail: layer-1 bwd single step + relu + FC (unchanged) ----------------
__launch_bounds__(384)
__global__ void final_k(const _Float16* __restrict__ out0,
                        const float* __restrict__ h1f,
                        const __half2* __restrict__ w1b,
                        const float* __restrict__ bih1b, const float* __restrict__ bhh1b,
                        const float* __restrict__ fcw, const float* __restrict__ fcb,
                        float* __restrict__ out) {
    __shared__ __align__(16) float s_x1[HC];
    __shared__ __align__(16) float s_xw[G_];
    __shared__ __align__(16) float s_hc[HC];
    __shared__ float s_red[8];
    const int tid = threadIdx.x;
    const int b = blockIdx.x;
    if (tid < HC)
        s_x1[tid] = (float)out0[((size_t)b * T_ + (T_ - 1)) * HC + tid];
    __syncthreads();
    {
        float acc0 = 0.f, acc1 = 0.f;
        const float2* xv = (const float2*)s_x1;
#pragma unroll 8
        for (int k2 = 0; k2 < 128; k2 += 2) {
            float2 w0 = __half22float2(w1b[k2 * G_ + tid]);
            float2 w1 = __half22float2(w1b[(k2 + 1) * G_ + tid]);
            float2 a0 = xv[k2], a1 = xv[k2 + 1];
            acc0 += a0.x * w0.x + a0.y * w0.y;
            acc1 += a1.x * w1.x + a1.y * w1.y;
        }
        s_xw[tid] = bih1b[tid] + acc0 + acc1;
    }
    __syncthreads();
    if (tid < H_) {
        int j = tid;
        float rg = sigm(s_xw[j] + bhh1b[j]);
        float zg = sigm(s_xw[H_ + j] + bhh1b[H_ + j]);
        float ng = tanh_f(s_xw[2 * H_ + j] + rg * bhh1b[2 * H_ + j]);
        float hb = (1.f - zg) * ng;
        s_hc[H_ + j] = fmaxf(hb, 0.f);
        s_hc[j] = fmaxf(h1f[(size_t)b * H_ + j], 0.f);
    }
    __syncthreads();
    if (tid < HC) {
        float hv = s_hc[tid];
        float p0 = hv * fcw[tid];
        float p1 = hv * fcw[HC + tid];
#pragma unroll
        for (int off = 32; off; off >>= 1) {
            p0 += __shfl_down(p0, off);
            p1 += __shfl_down(p1, off);
        }
        if ((tid & 63) == 0) { s_red[(tid >> 6) * 2] = p0; s_red[(tid >> 6) * 2 + 1] = p1; }
    }
    __syncthreads();
    if (tid == 0) {
        out[b * 2 + 0] = fcb[0] + s_red[0] + s_red[2] + s_red[4] + s_red[6];
        out[b * 2 + 1] = fcb[1] + s_red[1] + s_red[3] + s_red[5] + s_red[7];
    }
}

extern "C" void kernel_launch(void* const* d_in, const int* in_sizes, int n_in,
                              void* d_out, int out_size, void* d_ws, size_t ws_size,
                              hipStream_t stream) {
    (void)in_sizes; (void)n_in; (void)out_size; (void)ws_size;
    const float* x     = (const float*)d_in[0];
    const float* Wih0f = (const float*)d_in[1];
    const float* Whh0f = (const float*)d_in[2];
    const float* bih0f = (const float*)d_in[3];
    const float* bhh0f = (const float*)d_in[4];
    const float* Wih0b = (const float*)d_in[5];
    const float* Whh0b = (const float*)d_in[6];
    const float* bih0b = (const float*)d_in[7];
    const float* bhh0b = (const float*)d_in[8];
    const float* Wih1f = (const float*)d_in[9];
    const float* Whh1f = (const float*)d_in[10];
    const float* bih1f = (const float*)d_in[11];
    const float* bhh1f = (const float*)d_in[12];
    const float* Wih1b = (const float*)d_in[13];
    const float* bih1b = (const float*)d_in[15];
    const float* bhh1b = (const float*)d_in[16];
    const float* fcw   = (const float*)d_in[17];
    const float* fcb   = (const float*)d_in[18];

    char* ws = (char*)d_ws;
    _Float16* out0 = (_Float16*)(ws + O_OUT0);
    _Float16* xw1  = (_Float16*)(ws + O_XW1);
    __half2*  wp   = (__half2*)(ws + O_WP);
    float*    h1f  = (float*)(ws + O_H1F);
    _Float16* wf16 = (_Float16*)(ws + O_WF16);
    float*    out  = (float*)d_out;

    prep<<<240, 256, 0, stream>>>(Wih1f, wf16, Wih1b, wp);

    scan_l0<<<dim3(64, 2), 512, 0, stream>>>(x, Wih0f, Whh0f, bih0f, bhh0f,
                                             Wih0b, Whh0b, bih0b, bhh0b, out0);

    gemm_xw1<<<2048, 256, 0, stream>>>(out0, wf16, bih1f, xw1);

    scan_l1<<<64, 512, 0, stream>>>(xw1, Whh1f, bhh1f, h1f);

    final_k<<<256, 384, 0, stream>>>(out0, h1f, wp, bih1b, bhh1b, fcw, fcb, out);
}

// Round 16
// 551.912 us; speedup vs baseline: 1.2356x; 1.2356x over previous
//
#include <hip/hip_runtime.h>
#include <hip/hip_fp16.h>

#define B_  256
#define T_  512
#define I_  64
#define H_  128
#define G_  384
#define HC  256

// Workspace layout (stream-ordered aliasing: x16 occupies the head of the xw1
// region — gemm overwrites it only after scan_l0 has fully consumed x16).
#define O_OUT0 0ull
#define O_XW1  67108864ull
#define O_X16  O_XW1
#define O_WP   167772160ull
#define O_H1F  (O_WP + 196608ull)
#define O_WF16 (O_H1F + 131072ull)

typedef _Float16 h8 __attribute__((ext_vector_type(8)));
typedef _Float16 h2 __attribute__((ext_vector_type(2)));
typedef float    f4 __attribute__((ext_vector_type(4)));

#define MFMA16 __builtin_amdgcn_mfma_f32_16x16x32_f16

__device__ __forceinline__ float sigm(float x)   { return __builtin_amdgcn_rcpf(1.f + __expf(-x)); }
__device__ __forceinline__ float tanh_f(float x) { return 1.f - 2.f * __builtin_amdgcn_rcpf(1.f + __expf(2.f * x)); }

__device__ __forceinline__ void bar_lds() {
    asm volatile("s_waitcnt lgkmcnt(0)\n\ts_barrier" ::: "memory");
}

__device__ __forceinline__ h8 load_w8(const float* src) {
    f4 a = *(const f4*)src;
    f4 b = *(const f4*)(src + 4);
    h8 v;
    v[0]=(_Float16)a[0]; v[1]=(_Float16)a[1]; v[2]=(_Float16)a[2]; v[3]=(_Float16)a[3];
    v[4]=(_Float16)b[0]; v[5]=(_Float16)b[1]; v[6]=(_Float16)b[2]; v[7]=(_Float16)b[3];
    return v;
}

// Fused prep: x->fp16 (4096 blocks), Wih1f->fp16 (48), Wih1b pack-T (192).
__global__ void prep(const float* __restrict__ x, _Float16* __restrict__ x16,
                     const float* __restrict__ Wf, _Float16* __restrict__ wf16,
                     const float* __restrict__ W1b, __half2* __restrict__ wp) {
    const int bid = blockIdx.x;
    const int tid = threadIdx.x;
    if (bid < 4096) {
        int i = bid * 256 + tid;
        const float* s = x + (size_t)i * 8;
        f4 a = *(const f4*)s, b = *(const f4*)(s + 4);
        h8 v;
        v[0]=(_Float16)a[0]; v[1]=(_Float16)a[1]; v[2]=(_Float16)a[2]; v[3]=(_Float16)a[3];
        v[4]=(_Float16)b[0]; v[5]=(_Float16)b[1]; v[6]=(_Float16)b[2]; v[7]=(_Float16)b[3];
        *(h8*)(x16 + (size_t)i * 8) = v;
    } else if (bid < 4144) {
        int i = (bid - 4096) * 256 + tid;
        const float* s = Wf + (size_t)i * 8;
        f4 a = *(const f4*)s, b = *(const f4*)(s + 4);
        h8 v;
        v[0]=(_Float16)a[0]; v[1]=(_Float16)a[1]; v[2]=(_Float16)a[2]; v[3]=(_Float16)a[3];
        v[4]=(_Float16)b[0]; v[5]=(_Float16)b[1]; v[6]=(_Float16)b[2]; v[7]=(_Float16)b[3];
        *(h8*)(wf16 + (size_t)i * 8) = v;
    } else {
        int i = (bid - 4144) * 256 + tid;
        int c = i % G_;
        int k2 = i / G_;
        wp[i] = __halves2half2(__float2half(W1b[c * 256 + 2 * k2]),
                               __float2half(W1b[c * 256 + 2 * k2 + 1]));
    }
}

// ---------------- Layer-0 scan: 4 rows/block + 4-timestep-packed x-MFMAs ----------------
// Batches at A-rows {0,4,8,12}; valid h C-data = reg 0 of every lane.
// x-part packing: A-row r -> batch (r>>2), time-offset (r&3). One 6-MFMA set
// yields gates for FOUR steps: C reg j = step t+j (row lq*4+j -> batch lq, toff j).
// x read from fp16 x16 as raw h8 (no cvt -> loads stay in flight across steps).
// A-frag h reads broadcast via row ln15&12 (conflict-free). Flat MFMA chains.
#define L0_STEP(SB, DB, J, ...) do {                                          \
    h8 ah0 = *(const h8*)&s_h[SB][offh[0]];                                   \
    h8 ah1 = *(const h8*)&s_h[SB][offh[1]];                                   \
    h8 ah2 = *(const h8*)&s_h[SB][offh[2]];                                   \
    h8 ah3 = *(const h8*)&s_h[SB][offh[3]];                                   \
    f4 hRa = z4, hRb = z4, hZa = z4, hZb = z4, hNa = sHn4, hNb = z4;          \
    hRa = MFMA16(ah0, bh[0][0], hRa, 0, 0, 0);                                \
    hZa = MFMA16(ah0, bh[1][0], hZa, 0, 0, 0);                                \
    hNa = MFMA16(ah0, bh[2][0], hNa, 0, 0, 0);                                \
    hRb = MFMA16(ah2, bh[0][2], hRb, 0, 0, 0);                                \
    hZb = MFMA16(ah2, bh[1][2], hZb, 0, 0, 0);                                \
    hNb = MFMA16(ah2, bh[2][2], hNb, 0, 0, 0);                                \
    hRa = MFMA16(ah1, bh[0][1], hRa, 0, 0, 0);                                \
    hZa = MFMA16(ah1, bh[1][1], hZa, 0, 0, 0);                                \
    hNa = MFMA16(ah1, bh[2][1], hNa, 0, 0, 0);                                \
    hRb = MFMA16(ah3, bh[0][3], hRb, 0, 0, 0);                                \
    hZb = MFMA16(ah3, bh[1][3], hZb, 0, 0, 0);                                \
    hNb = MFMA16(ah3, bh[2][3], hNb, 0, 0, 0);                                \
    float r_ = sigm(gR[J] + hRa[0] + hRb[0]);                                 \
    float z_ = sigm(gZ[J] + hZa[0] + hZb[0]);                                 \
    float n_ = tanh_f(gN[J] + r_ * (hNa[0] + hNb[0]));                        \
    float h_ = n_ + z_ * (hF - n_);                                           \
    hF = h_;                                                                  \
    s_h[DB][offw0] = (_Float16)h_;                                            \
    *op = (_Float16)h_; op += ostep;                                          \
    __VA_ARGS__                                                               \
    bar_lds();                                                                \
} while (0)

__launch_bounds__(512, 1)
__global__ void scan_l0(const _Float16* __restrict__ x16,
                        const float* __restrict__ Wih_f, const float* __restrict__ Whh_f,
                        const float* __restrict__ bih_f, const float* __restrict__ bhh_f,
                        const float* __restrict__ Wih_b, const float* __restrict__ Whh_b,
                        const float* __restrict__ bih_b, const float* __restrict__ bhh_b,
                        _Float16* __restrict__ out0) {
    __shared__ __align__(16) _Float16 s_h[2][16 * 128];

    const int tid  = threadIdx.x;
    const int lane = tid & 63;
    const int w    = tid >> 6;           // 0..7
    const int dir  = blockIdx.y;
    const int b0   = blockIdx.x * 4;

    const float* Wih = dir ? Wih_b : Wih_f;
    const float* Whh = dir ? Whh_b : Whh_f;
    const float* bih = dir ? bih_b : bih_f;
    const float* bhh = dir ? bhh_b : bhh_f;

    for (int i = tid; i < 2 * 16 * 128; i += 512) ((_Float16*)s_h)[i] = (_Float16)0.f;

    const int ln15 = lane & 15;
    const int lq   = lane >> 4;
    const int col  = 16 * w + ln15;

    h8 bh[3][4], bx[3][2];
    float seedR = bih[col] + bhh[col];
    float seedZ = bih[H_ + col] + bhh[H_ + col];
    float bihN  = bih[2 * H_ + col];
    float bhhN  = bhh[2 * H_ + col];
#pragma unroll
    for (int g = 0; g < 3; g++) {
        int n = g * H_ + col;
#pragma unroll
        for (int kt = 0; kt < 4; kt++) bh[g][kt] = load_w8(Whh + (size_t)n * H_ + kt * 32 + lq * 8);
#pragma unroll
        for (int kt = 0; kt < 2; kt++) bx[g][kt] = load_w8(Wih + (size_t)n * I_ + kt * 32 + lq * 8);
    }
    const int arow = ln15 & 12;          // broadcast A-read row (conflict-free)
    int offh[4];
#pragma unroll
    for (int kt = 0; kt < 4; kt++)
        offh[kt] = arow * 128 + (((kt * 4 + lq) ^ arow) & 15) * 8;
    const int row0  = lq * 4;
    const int offw0 = row0 * 128 + ((((col >> 3) ^ row0) & 15)) * 8 + (col & 7);

    const f4 z4 = (f4){0.f, 0.f, 0.f, 0.f};
    const f4 sR4 = (f4){seedR, seedR, seedR, seedR};
    const f4 sZ4 = (f4){seedZ, seedZ, seedZ, seedZ};
    const f4 sXn4 = (f4){bihN, bihN, bihN, bihN};
    const f4 sHn4 = (f4){bhhN, bhhN, bhhN, bhhN};

    // packed x lane pointer: batch = b0+(ln15>>2), time-offset = ln15&3.
    const int toff = ln15 & 3;
    const _Float16* xp = x16 + ((size_t)(b0 + (ln15 >> 2)) * T_ + (dir ? (T_ - 1 - toff) : toff)) * I_ + lq * 8;
    const int xstep = dir ? -(4 * I_) : (4 * I_);   // 4 timesteps per iter

    _Float16* op = out0 + ((size_t)(b0 + lq) * T_ + (dir ? (T_ - 1) : 0)) * HC + dir * H_ + col;
    const int ostep = dir ? -HC : HC;

    float hF = 0.f;
    f4 gR, gZ, gN;        // current gates, component j = step t+j
    f4 ngR, ngZ, ngN;     // next iter's gates
    h8 xvA0, xvA1;        // x for steps t+4..t+7 (raw fp16 bits)
    {   // prologue: gates(0..3) from x(0..3); xvA <- x(4..7)
        h8 xc0 = *(const h8*)(xp);
        h8 xc1 = *(const h8*)(xp + 32);
        xp += xstep;
        xvA0 = *(const h8*)(xp);
        xvA1 = *(const h8*)(xp + 32);
        xp += xstep;      // now points at t+8 block
        gR = sR4; gZ = sZ4; gN = sXn4;
        gR = MFMA16(xc0, bx[0][0], gR, 0, 0, 0);
        gZ = MFMA16(xc0, bx[1][0], gZ, 0, 0, 0);
        gN = MFMA16(xc0, bx[2][0], gN, 0, 0, 0);
        gR = MFMA16(xc1, bx[0][1], gR, 0, 0, 0);
        gZ = MFMA16(xc1, bx[1][1], gZ, 0, 0, 0);
        gN = MFMA16(xc1, bx[2][1], gN, 0, 0, 0);
    }
    __syncthreads();

#pragma unroll 1
    for (int t = 0; t < T_; t += 4) {
        L0_STEP(0, 1, 0,
            if (t + 4 < T_) {   // next gate quad from xvA (off critical path)
                ngR = sR4; ngZ = sZ4; ngN = sXn4;
                ngR = MFMA16(xvA0, bx[0][0], ngR, 0, 0, 0);
                ngZ = MFMA16(xvA0, bx[1][0], ngZ, 0, 0, 0);
                ngN = MFMA16(xvA0, bx[2][0], ngN, 0, 0, 0);
                ngR = MFMA16(xvA1, bx[0][1], ngR, 0, 0, 0);
                ngZ = MFMA16(xvA1, bx[1][1], ngZ, 0, 0, 0);
                ngN = MFMA16(xvA1, bx[2][1], ngN, 0, 0, 0);
            }
        );
        L0_STEP(1, 0, 1, );
        L0_STEP(0, 1, 2,
            if (t + 8 < T_) {   // reload xvA <- x(t+8..t+11), raw bits
                xvA0 = *(const h8*)(xp);
                xvA1 = *(const h8*)(xp + 32);
                xp += xstep;
            }
        );
        L0_STEP(1, 0, 3,
            gR = ngR; gZ = ngZ; gN = ngN;
        );
    }
}

// ---------------- MFMA GEMM v4: per-block M=64, full N=384 (unchanged) ----------------
__launch_bounds__(256, 1)
__global__ void gemm_xw1(const _Float16* __restrict__ A,
                         const _Float16* __restrict__ Bw,
                         const float* __restrict__ bias,
                         _Float16* __restrict__ C) {
    __shared__ __align__(16) _Float16 sA[2][64 * 64];
    __shared__ __align__(16) _Float16 sB[2][384 * 64];
    const int tid  = threadIdx.x;
    const int lane = tid & 63;
    const int w    = tid >> 6;
    const int wm   = w & 1, wn = w >> 1;
    const int ln15 = lane & 15, lq = lane >> 4;
    const size_t m0 = (size_t)blockIdx.x * 64;

    f4 acc[2][12] = {};

    int aRow[2], aG[2], aOff[2];
#pragma unroll
    for (int k = 0; k < 2; k++) {
        int idx = k * 256 + tid;
        aRow[k] = idx >> 3; aG[k] = idx & 7;
        aOff[k] = aRow[k] * 64 + ((aG[k] ^ (aRow[k] & 7)) & 7) * 8;
    }
    int bRow[12], bG[12], bOff[12];
#pragma unroll
    for (int k = 0; k < 12; k++) {
        int idx = k * 256 + tid;
        bRow[k] = idx >> 3; bG[k] = idx & 7;
        bOff[k] = bRow[k] * 64 + ((bG[k] ^ (bRow[k] & 7)) & 7) * 8;
    }
    int offA[2][2], offB[12][2];
#pragma unroll
    for (int mt = 0; mt < 2; mt++)
#pragma unroll
        for (int kt = 0; kt < 2; kt++) {
            int row = wm * 32 + mt * 16 + ln15;
            offA[mt][kt] = row * 64 + (((kt * 4 + lq) ^ (row & 7)) & 7) * 8;
        }
#pragma unroll
    for (int nt = 0; nt < 12; nt++)
#pragma unroll
        for (int kt = 0; kt < 2; kt++) {
            int row = wn * 192 + nt * 16 + ln15;
            offB[nt][kt] = row * 64 + (((kt * 4 + lq) ^ (row & 7)) & 7) * 8;
        }

    {   // prologue: chunk 0 -> buf 0
        h8 av[2], bv[12];
#pragma unroll
        for (int k = 0; k < 2; k++) av[k] = *(const h8*)(A + (m0 + aRow[k]) * 256 + aG[k] * 8);
#pragma unroll
        for (int k = 0; k < 12; k++) bv[k] = *(const h8*)(Bw + (size_t)bRow[k] * 256 + bG[k] * 8);
#pragma unroll
        for (int k = 0; k < 2; k++) *(h8*)&sA[0][aOff[k]] = av[k];
#pragma unroll
        for (int k = 0; k < 12; k++) *(h8*)&sB[0][bOff[k]] = bv[k];
        bar_lds();
    }

#pragma unroll
    for (int c = 0; c < 4; c++) {
        const int cur = c & 1;
        h8 av[2], bv[12];
        if (c < 3) {
#pragma unroll
            for (int k = 0; k < 2; k++)
                av[k] = *(const h8*)(A + (m0 + aRow[k]) * 256 + (c + 1) * 64 + aG[k] * 8);
#pragma unroll
            for (int k = 0; k < 12; k++)
                bv[k] = *(const h8*)(Bw + (size_t)bRow[k] * 256 + (c + 1) * 64 + bG[k] * 8);
        }
#pragma unroll
        for (int kt = 0; kt < 2; kt++) {
            h8 af0 = *(const h8*)&sA[cur][offA[0][kt]];
            h8 af1 = *(const h8*)&sA[cur][offA[1][kt]];
#pragma unroll
            for (int nt = 0; nt < 12; nt++) {
                h8 bf = *(const h8*)&sB[cur][offB[nt][kt]];
                acc[0][nt] = MFMA16(af0, bf, acc[0][nt], 0, 0, 0);
                acc[1][nt] = MFMA16(af1, bf, acc[1][nt], 0, 0, 0);
            }
        }
        if (c < 3) {
#pragma unroll
            for (int k = 0; k < 2; k++) *(h8*)&sA[cur ^ 1][aOff[k]] = av[k];
#pragma unroll
            for (int k = 0; k < 12; k++) *(h8*)&sB[cur ^ 1][bOff[k]] = bv[k];
            bar_lds();
        }
    }
#pragma unroll
    for (int nt = 0; nt < 12; nt++) {
        int col = wn * 192 + nt * 16 + ln15;
        float bb = bias[col];
        int pcol = (col < 256) ? ((col & 127) * 2 + (col >> 7)) : col;
#pragma unroll
        for (int mt = 0; mt < 2; mt++) {
            size_t row = m0 + wm * 32 + mt * 16 + lq * 4;
#pragma unroll
            for (int reg = 0; reg < 4; reg++)
                C[(row + reg) * G_ + pcol] = (_Float16)(acc[mt][nt][reg] + bb);
        }
    }
}

// ---------------- Layer-1 fwd scan: 8 waves, 4 rows/block (known-good) ----------------
__launch_bounds__(512, 1)
__global__ void scan_l1(const _Float16* __restrict__ xw1,
                        const float* __restrict__ Whh,
                        const float* __restrict__ bhh,
                        float* __restrict__ h1f) {
    __shared__ __align__(16) _Float16 s_h[2][16 * 128];

    const int tid  = threadIdx.x;
    const int lane = tid & 63;
    const int w    = tid >> 6;
    const int b0   = blockIdx.x * 4;

    for (int i = tid; i < 2 * 16 * 128; i += 512) ((_Float16*)s_h)[i] = (_Float16)0.f;

    const int ln15 = lane & 15;
    const int lq   = lane >> 4;
    const int col  = 16 * w + ln15;

    h8 bh[3][4];
    float bhhF[3];
#pragma unroll
    for (int g = 0; g < 3; g++) {
        int n = g * H_ + col;
        bhhF[g] = bhh[n];
#pragma unroll
        for (int kt = 0; kt < 4; kt++) bh[g][kt] = load_w8(Whh + (size_t)n * H_ + kt * 32 + lq * 8);
    }
    const int arow = ln15 & 12;
    int offh[4];
#pragma unroll
    for (int kt = 0; kt < 4; kt++)
        offh[kt] = arow * 128 + (((kt * 4 + lq) ^ arow) & 15) * 8;
    const int row0  = lq * 4;
    const int offw0 = row0 * 128 + ((((col >> 3) ^ row0) & 15)) * 8 + (col & 7);

    const _Float16* rzbase = xw1 + ((size_t)(b0 + lq) * T_) * G_ + 2 * col;
    const _Float16* nbase  = xw1 + ((size_t)(b0 + lq) * T_) * G_ + 256 + col;

    const f4 z4 = (f4){0.f, 0.f, 0.f, 0.f};
    const f4 sR4 = (f4){bhhF[0], bhhF[0], bhhF[0], bhhF[0]};
    const f4 sZ4 = (f4){bhhF[1], bhhF[1], bhhF[1], bhhF[1]};
    const f4 sN4 = (f4){bhhF[2], bhhF[2], bhhF[2], bhhF[2]};

    __syncthreads();

    float hF = 0.f;
    h2 rzA = *(const h2*)(rzbase);
    h2 rzB = *(const h2*)(rzbase + G_);
    _Float16 nA = *nbase;
    _Float16 nB = *(nbase + G_);
    const _Float16* rzP2 = rzbase + 2 * G_;
    const _Float16* nP2  = nbase  + 2 * G_;
    const _Float16* rzP3 = rzbase + 3 * G_;
    const _Float16* nP3  = nbase  + 3 * G_;

#pragma unroll 1
    for (int s = 0; s < T_; s += 2) {
        {   // even step: read s_h[0] -> write s_h[1]
            h8 ah0 = *(const h8*)&s_h[0][offh[0]];
            h8 ah1 = *(const h8*)&s_h[0][offh[1]];
            h8 ah2 = *(const h8*)&s_h[0][offh[2]];
            h8 ah3 = *(const h8*)&s_h[0][offh[3]];
            float xr = (float)rzA[0], xz = (float)rzA[1], xn = (float)nA;
            if (s + 2 < T_) {
                rzA = *(const h2*)rzP2;
                nA  = *nP2;
                rzP2 += 2 * G_; nP2 += 2 * G_;
            }
            f4 hRa = sR4, hRb = z4, hZa = sZ4, hZb = z4, hNa = sN4, hNb = z4;
            hRa = MFMA16(ah0, bh[0][0], hRa, 0, 0, 0);
            hZa = MFMA16(ah0, bh[1][0], hZa, 0, 0, 0);
            hNa = MFMA16(ah0, bh[2][0], hNa, 0, 0, 0);
            hRb = MFMA16(ah2, bh[0][2], hRb, 0, 0, 0);
            hZb = MFMA16(ah2, bh[1][2], hZb, 0, 0, 0);
            hNb = MFMA16(ah2, bh[2][2], hNb, 0, 0, 0);
            hRa = MFMA16(ah1, bh[0][1], hRa, 0, 0, 0);
            hZa = MFMA16(ah1, bh[1][1], hZa, 0, 0, 0);
            hNa = MFMA16(ah1, bh[2][1], hNa, 0, 0, 0);
            hRb = MFMA16(ah3, bh[0][3], hRb, 0, 0, 0);
            hZb = MFMA16(ah3, bh[1][3], hZb, 0, 0, 0);
            hNb = MFMA16(ah3, bh[2][3], hNb, 0, 0, 0);
            float r = sigm(xr + hRa[0] + hRb[0]);
            float z = sigm(xz + hZa[0] + hZb[0]);
            float n = tanh_f(xn + r * (hNa[0] + hNb[0]));
            float h = n + z * (hF - n);
            hF = h;
            s_h[1][offw0] = (_Float16)h;
            bar_lds();
        }
        {   // odd step: read s_h[1] -> write s_h[0]
            h8 ah0 = *(const h8*)&s_h[1][offh[0]];
            h8 ah1 = *(const h8*)&s_h[1][offh[1]];
            h8 ah2 = *(const h8*)&s_h[1][offh[2]];
            h8 ah3 = *(const h8*)&s_h[1][offh[3]];
            float xr = (float)rzB[0], xz = (float)rzB[1], xn = (float)nB;
            if (s + 3 < T_) {
                rzB = *(const h2*)rzP3;
                nB  = *nP3;
                rzP3 += 2 * G_; nP3 += 2 * G_;
            }
            f4 hRa = sR4, hRb = z4, hZa = sZ4, hZb = z4, hNa = sN4, hNb = z4;
            hRa = MFMA16(ah0, bh[0][0], hRa, 0, 0, 0);
            hZa = MFMA16(ah0, bh[1][0], hZa, 0, 0, 0);
            hNa = MFMA16(ah0, bh[2][0], hNa, 0, 0, 0);
            hRb = MFMA16(ah2, bh[0][2], hRb, 0, 0, 0);
            hZb = MFMA16(ah2, bh[1][2], hZb, 0, 0, 0);
            hNb = MFMA16(ah2, bh[2][2], hNb, 0, 0, 0);
            hRa = MFMA16(ah1, bh[0][1], hRa, 0, 0, 0);
            hZa = MFMA16(ah1, bh[1][1], hZa, 0, 0, 0);
            hNa = MFMA16(ah1, bh[2][1], hNa, 0, 0, 0);
            hRb = MFMA16(ah3, bh[0][3], hRb, 0, 0, 0);
            hZb = MFMA16(ah3, bh[1][3], hZb, 0, 0, 0);
            hNb = MFMA16(ah3, bh[2][3], hNb, 0, 0, 0);
            float r = sigm(xr + hRa[0] + hRb[0]);
            float z = sigm(xz + hZa[0] + hZb[0]);
            float n = tanh_f(xn + r * (hNa[0] + hNb[0]));
            float h = n + z * (hF - n);
            hF = h;
            s_h[0][offw0] = (_Float16)h;
            bar_lds();
        }
    }
    h1f[(size_t)(b0 + lq) * H_ + col] = hF;
}

// ---------------- Tail: layer-1 bwd single step + relu + FC (unchanged) ----------------
__launch_bounds__(384)
__global__ void final_k(const _Float16* __restrict__ out0,
                        const float* __restrict__ h1f,
                        const __half2* __restrict__ w1b,
                        const float* __restrict__ bih1b, const float* __restrict__ bhh1b,
                        const float* __restrict__ fcw, const float* __restrict__ fcb,
                        float* __restrict__ out) {
    __shared__ __align__(16) float s_x1[HC];
    __shared__ __align__(16) float s_xw[G_];
    __shared__ __align__(16) float s_hc[HC];
    __shared__ float s_red[8];
    const int tid = threadIdx.x;
    const int b = blockIdx.x;
    if (tid < HC)
        s_x1[tid] = (float)out0[((size_t)b * T_ + (T_ - 1)) * HC + tid];
    __syncthreads();
    {
        float acc0 = 0.f, acc1 = 0.f;
        const float2* xv = (const float2*)s_x1;
#pragma unroll 8
        for (int k2 = 0; k2 < 128; k2 += 2) {
            float2 w0 = __half22float2(w1b[k2 * G_ + tid]);
            float2 w1 = __half22float2(w1b[(k2 + 1) * G_ + tid]);
            float2 a0 = xv[k2], a1 = xv[k2 + 1];
            acc0 += a0.x * w0.x + a0.y * w0.y;
            acc1 += a1.x * w1.x + a1.y * w1.y;
        }
        s_xw[tid] = bih1b[tid] + acc0 + acc1;
    }
    __syncthreads();
    if (tid < H_) {
        int j = tid;
        float rg = sigm(s_xw[j] + bhh1b[j]);
        float zg = sigm(s_xw[H_ + j] + bhh1b[H_ + j]);
        float ng = tanh_f(s_xw[2 * H_ + j] + rg * bhh1b[2 * H_ + j]);
        float hb = (1.f - zg) * ng;
        s_hc[H_ + j] = fmaxf(hb, 0.f);
        s_hc[j] = fmaxf(h1f[(size_t)b * H_ + j], 0.f);
    }
    __syncthreads();
    if (tid < HC) {
        float hv = s_hc[tid];
        float p0 = hv * fcw[tid];
        float p1 = hv * fcw[HC + tid];
#pragma unroll
        for (int off = 32; off; off >>= 1) {
            p0 += __shfl_down(p0, off);
            p1 += __shfl_down(p1, off);
        }
        if ((tid & 63) == 0) { s_red[(tid >> 6) * 2] = p0; s_red[(tid >> 6) * 2 + 1] = p1; }
    }
    __syncthreads();
    if (tid == 0) {
        out[b * 2 + 0] = fcb[0] + s_red[0] + s_red[2] + s_red[4] + s_red[6];
        out[b * 2 + 1] = fcb[1] + s_red[1] + s_red[3] + s_red[5] + s_red[7];
    }
}

extern "C" void kernel_launch(void* const* d_in, const int* in_sizes, int n_in,
                              void* d_out, int out_size, void* d_ws, size_t ws_size,
                              hipStream_t stream) {
    (void)in_sizes; (void)n_in; (void)out_size; (void)ws_size;
    const float* x     = (const float*)d_in[0];
    const float* Wih0f = (const float*)d_in[1];
    const float* Whh0f = (const float*)d_in[2];
    const float* bih0f = (const float*)d_in[3];
    const float* bhh0f = (const float*)d_in[4];
    const float* Wih0b = (const float*)d_in[5];
    const float* Whh0b = (const float*)d_in[6];
    const float* bih0b = (const float*)d_in[7];
    const float* bhh0b = (const float*)d_in[8];
    const float* Wih1f = (const float*)d_in[9];
    const float* Whh1f = (const float*)d_in[10];
    const float* bih1f = (const float*)d_in[11];
    const float* bhh1f = (const float*)d_in[12];
    const float* Wih1b = (const float*)d_in[13];
    const float* bih1b = (const float*)d_in[15];
    const float* bhh1b = (const float*)d_in[16];
    const float* fcw   = (const float*)d_in[17];
    const float* fcb   = (const float*)d_in[18];

    char* ws = (char*)d_ws;
    _Float16* out0 = (_Float16*)(ws + O_OUT0);
    _Float16* xw1  = (_Float16*)(ws + O_XW1);
    _Float16* x16  = (_Float16*)(ws + O_X16);
    __half2*  wp   = (__half2*)(ws + O_WP);
    float*    h1f  = (float*)(ws + O_H1F);
    _Float16* wf16 = (_Float16*)(ws + O_WF16);
    float*    out  = (float*)d_out;

    prep<<<4336, 256, 0, stream>>>(x, x16, Wih1f, wf16, Wih1b, wp);

    scan_l0<<<dim3(64, 2), 512, 0, stream>>>(x16, Wih0f, Whh0f, bih0f, bhh0f,
                                             Wih0b, Whh0b, bih0b, bhh0b, out0);

    gemm_xw1<<<2048, 256, 0, stream>>>(out0, wf16, bih1f, xw1);

    scan_l1<<<64, 512, 0, stream>>>(xw1, Whh1f, bhh1f, h1f);

    final_k<<<256, 384, 0, stream>>>(out0, h1f, wp, bih1b, bhh1b, fcw, fcb, out);
}